// Round 1
// 98.596 us; speedup vs baseline: 1.0586x; 1.0586x over previous
//
#include <hip/hip_runtime.h>
#include <math.h>

#define NCLS 9
#define DIM 768
#define NPIX 65536   // 4 * 128 * 128

// ---- workspace layout (bytes), no memset needed ----
#define OFF_LAB     ((size_t)0)        // uchar[65536]          = 65536
#define OFF_HIST    ((size_t)65536)    // int[256*9]            = 9216   -> 74752
#define OFF_SUMS    ((size_t)74752)    // float[9*768]          = 27648  -> 102400
#define OFF_SUMSQ   ((size_t)102400)   // float[16] (zeroed by k0)
#define OFF_LOSS    ((size_t)102464)   // float[4]  (zeroed by k0)
#define OFF_DONE    ((size_t)102480)   // uint[4]   (zeroed by k0)
#define OFF_LOGITS  ((size_t)131072)   // float[9*65536]        = 2359296 -> 2490368
// total ~2.5 MB

__device__ __forceinline__ float waveReduceSum(float v) {
#pragma unroll
  for (int off = 32; off > 0; off >>= 1) v += __shfl_down(v, off, 64);
  return v;
}

// K0: downsample labels -> uchar lab[n]; per-block histogram -> hist[block][9];
// block 0 zero-inits sumsq/lossacc/done for downstream kernels.
__global__ void k0_lab(const int* __restrict__ label, unsigned char* __restrict__ lab,
                       int* __restrict__ hist, float* __restrict__ sumsq,
                       float* __restrict__ lossacc, unsigned int* __restrict__ done) {
  __shared__ int h[NCLS];
  int tid = threadIdx.x;
  if (tid < NCLS) h[tid] = 0;
  __syncthreads();
  int n = blockIdx.x * 256 + tid;
  int b = n >> 14, r = (n >> 7) & 127, cc = n & 127;
  int c = label[b * 262144 + r * 2048 + cc * 4];
  lab[n] = (unsigned char)c;
  atomicAdd(&h[c], 1);
  if (blockIdx.x == 0) {
    if (tid < 16) sumsq[tid] = 0.f;
    else if (tid == 16) lossacc[0] = 0.f;
    else if (tid == 17) done[0] = 0u;
  }
  __syncthreads();
  if (tid < NCLS) hist[blockIdx.x * NCLS + tid] = h[tid];
}

// K1: per-class segment sums. One block per feature dim d. uchar4 labels (4x less
// L2 label traffic than int4).
__global__ void k1_segsum(const float4* __restrict__ feat4, const uchar4* __restrict__ lab4,
                          float* __restrict__ sums) {
  int d = blockIdx.x;
  int tid = threadIdx.x;
  float acc[NCLS];
#pragma unroll
  for (int k = 0; k < NCLS; ++k) acc[k] = 0.f;
  for (int b = 0; b < 4; ++b) {
    const float4* fp = feat4 + (size_t)(b * DIM + d) * 4096;
    const uchar4* lp = lab4 + b * 4096;
#pragma unroll 4
    for (int i = 0; i < 16; ++i) {
      int p = tid + i * 256;
      float4 f = fp[p];
      uchar4 l = lp[p];
      int lx = l.x, ly = l.y, lz = l.z, lw = l.w;
#pragma unroll
      for (int k = 0; k < NCLS; ++k) {
        acc[k] += (lx == k) ? f.x : 0.f;
        acc[k] += (ly == k) ? f.y : 0.f;
        acc[k] += (lz == k) ? f.z : 0.f;
        acc[k] += (lw == k) ? f.w : 0.f;
      }
    }
  }
  __shared__ float red[4][NCLS];
#pragma unroll
  for (int k = 0; k < NCLS; ++k) acc[k] = waveReduceSum(acc[k]);
  int lane = tid & 63, w = tid >> 6;
  if (lane == 0) {
#pragma unroll
    for (int k = 0; k < NCLS; ++k) red[w][k] = acc[k];
  }
  __syncthreads();
  if (tid < NCLS)
    sums[tid * DIM + d] = red[0][tid] + red[1][tid] + red[2][tid] + red[3][tid];
}

// K3 (fused k2+k3+k4): every block redundantly computes the normalized prototypes
// into LDS (replaces the single-block k2), then does 4-way split-K over dims with
// the partial combine through LDS (replaces the 19MB global `part` round-trip),
// writing logits + per-class sum-of-squares via atomics.
__global__ void __launch_bounds__(1024) k3_fused(const float* __restrict__ sums,
                                                 const int* __restrict__ hist,
                                                 const float* __restrict__ proto,
                                                 const float* __restrict__ feat,
                                                 float* __restrict__ logits,
                                                 float* __restrict__ sumsq) {
  __shared__ float pl[DIM * 12];      // 36864 B: protoT, then reused for partial combine
  __shared__ float cpart[32][NCLS];
  __shared__ float cnt[NCLS];
  __shared__ float red12[12][NCLS];
  __shared__ float invn[NCLS];
  __shared__ float red4[4][NCLS];
  int tid = threadIdx.x;

  // ---- prologue: counts from per-block hist ----
  if (tid < 288) {
    int c = tid % NCLS, g = tid / NCLS;  // g in 0..31
    int s = 0;
#pragma unroll
    for (int j = 0; j < 8; ++j) s += hist[(g * 8 + j) * NCLS + c];
    cpart[g][c] = (float)s;
  }
  __syncthreads();
  if (tid < NCLS) {
    float s = 0.f;
#pragma unroll
    for (int g = 0; g < 32; ++g) s += cpart[g][tid];
    cnt[tid] = s;
  }
  __syncthreads();

  // ---- prologue: protos = l2norm(0.99*mean + 0.01*proto) -> pl[d*12 + c] ----
  float v[NCLS];
  if (tid < DIM) {
#pragma unroll
    for (int c = 0; c < NCLS; ++c)
      v[c] = 0.99f * (sums[c * DIM + tid] / cnt[c]) + 0.01f * proto[c * DIM + tid];
    int lane = tid & 63, w = tid >> 6;  // w in 0..11
#pragma unroll
    for (int c = 0; c < NCLS; ++c) {
      float q = waveReduceSum(v[c] * v[c]);
      if (lane == 0) red12[w][c] = q;
    }
  }
  __syncthreads();
  if (tid < NCLS) {
    float t = 0.f;
#pragma unroll
    for (int w2 = 0; w2 < 12; ++w2) t += red12[w2][tid];
    invn[tid] = 1.f / fmaxf(sqrtf(t), 1e-12f);
  }
  __syncthreads();
  if (tid < DIM) {
#pragma unroll
    for (int c = 0; c < NCLS; ++c) pl[tid * 12 + c] = v[c] * invn[c];
  }
  __syncthreads();

  // ---- main: split-K logits. s = dim-quarter, p = pixel within block's 256 ----
  int s = tid >> 8, p = tid & 255;
  int n = blockIdx.x * 256 + p;
  int b = n >> 14, pp = n & 16383;
  const float* fp = feat + ((size_t)(b * DIM + s * 192)) * 16384 + pp;
  const float* plbase = pl + (size_t)s * 192 * 12;
  float a0 = 0, a1 = 0, a2 = 0, a3 = 0, a4 = 0, a5 = 0, a6 = 0, a7 = 0, a8 = 0;
#pragma unroll 4
  for (int dd = 0; dd < 192; ++dd) {
    float f = fp[(size_t)dd * 16384];
    const float4* pr = (const float4*)(plbase + dd * 12);
    float4 q0 = pr[0];
    float4 q1 = pr[1];
    float q8 = plbase[dd * 12 + 8];
    a0 += q0.x * f; a1 += q0.y * f; a2 += q0.z * f; a3 += q0.w * f;
    a4 += q1.x * f; a5 += q1.y * f; a6 += q1.z * f; a7 += q1.w * f;
    a8 += q8 * f;
  }
  __syncthreads();  // pl reads done; safe to reuse as partial buffer
  if (s > 0) {
    float* rp = pl + (size_t)(s - 1) * 2304 + p * 9;
    rp[0] = a0; rp[1] = a1; rp[2] = a2; rp[3] = a3; rp[4] = a4;
    rp[5] = a5; rp[6] = a6; rp[7] = a7; rp[8] = a8;
  }
  __syncthreads();
  if (s == 0) {
#pragma unroll
    for (int q = 0; q < 3; ++q) {
      const float* rp = pl + (size_t)q * 2304 + p * 9;
      a0 += rp[0]; a1 += rp[1]; a2 += rp[2]; a3 += rp[3]; a4 += rp[4];
      a5 += rp[5]; a6 += rp[6]; a7 += rp[7]; a8 += rp[8];
    }
    float* outp = logits + n;
    outp[0 * NPIX] = a0; outp[1 * NPIX] = a1; outp[2 * NPIX] = a2;
    outp[3 * NPIX] = a3; outp[4 * NPIX] = a4; outp[5 * NPIX] = a5;
    outp[6 * NPIX] = a6; outp[7 * NPIX] = a7; outp[8 * NPIX] = a8;
    float ss[NCLS] = {a0 * a0, a1 * a1, a2 * a2, a3 * a3, a4 * a4,
                      a5 * a5, a6 * a6, a7 * a7, a8 * a8};
#pragma unroll
    for (int c = 0; c < NCLS; ++c) ss[c] = waveReduceSum(ss[c]);
    int lane = tid & 63, w = tid >> 6;  // w in 0..3 (tid < 256 here)
    if (lane == 0) {
#pragma unroll
      for (int c = 0; c < NCLS; ++c) red4[w][c] = ss[c];
    }
  }
  __syncthreads();
  if (tid < NCLS)
    atomicAdd(&sumsq[tid], red4[0][tid] + red4[1][tid] + red4[2][tid] + red4[3][tid]);
}

// K5: per-pixel loss + fused finalize via done-ticket.
__global__ void k5_loss(const float4* __restrict__ logits4, const uchar4* __restrict__ lab4,
                        const float* __restrict__ sumsq, float* __restrict__ lossacc,
                        unsigned int* __restrict__ done, float* __restrict__ out) {
  int t = blockIdx.x * 256 + threadIdx.x;  // float4 index over 16384
  int tid = threadIdx.x;
  float scale[NCLS];
#pragma unroll
  for (int c = 0; c < NCLS; ++c) scale[c] = 10.f / fmaxf(sqrtf(sumsq[c]), 1e-12f);
  float arr[NCLS][4];
#pragma unroll
  for (int c = 0; c < NCLS; ++c) {
    float4 v = logits4[(size_t)c * 16384 + t];
    arr[c][0] = v.x; arr[c][1] = v.y; arr[c][2] = v.z; arr[c][3] = v.w;
  }
  uchar4 lb = lab4[t];
  int lv[4] = {lb.x, lb.y, lb.z, lb.w};
  float lsum = 0.f;
#pragma unroll
  for (int j = 0; j < 4; ++j) {
    int l = lv[j];
    int lc = (l == 7) ? 6 : l;
    float sumE = 0.f, picked = 0.f;
#pragma unroll
    for (int c = 0; c < NCLS; ++c) {
      float pf = (c == 2) ? ((lc == 2) ? 1.f : 0.f) : arr[c][j] * scale[c];
      sumE += __expf(pf);
      picked += (c == lc) ? pf : 0.f;
    }
    lsum += __logf(sumE) - picked;
  }
  lsum = waveReduceSum(lsum);
  __shared__ float red[4];
  int lane = tid & 63, w = tid >> 6;
  if (lane == 0) red[w] = lsum;
  __syncthreads();
  if (tid == 0) {
    atomicAdd(lossacc, red[0] + red[1] + red[2] + red[3]);
    __threadfence();
    unsigned int ticket = atomicAdd(done, 1u);
    if (ticket == gridDim.x - 1) {
      __threadfence();
      float total = __hip_atomic_load(lossacc, __ATOMIC_ACQUIRE, __HIP_MEMORY_SCOPE_AGENT);
      out[0] = total * (1.f / (float)NPIX);
    }
  }
}

extern "C" void kernel_launch(void* const* d_in, const int* in_sizes, int n_in,
                              void* d_out, int out_size, void* d_ws, size_t ws_size,
                              hipStream_t stream) {
  // inputs: 0=cls_score (unused), 1=label, 2=gt_lucas (unused), 3=features, 4=prototypes
  const int* label = (const int*)d_in[1];
  const float* feat = (const float*)d_in[3];
  const float* proto = (const float*)d_in[4];
  char* ws = (char*)d_ws;
  unsigned char* lab = (unsigned char*)(ws + OFF_LAB);
  int* hist = (int*)(ws + OFF_HIST);
  float* sums = (float*)(ws + OFF_SUMS);
  float* sumsq = (float*)(ws + OFF_SUMSQ);
  float* lossacc = (float*)(ws + OFF_LOSS);
  unsigned int* done = (unsigned int*)(ws + OFF_DONE);
  float* logits = (float*)(ws + OFF_LOGITS);

  k0_lab<<<NPIX / 256, 256, 0, stream>>>(label, lab, hist, sumsq, lossacc, done);
  k1_segsum<<<DIM, 256, 0, stream>>>((const float4*)feat, (const uchar4*)lab, sums);
  k3_fused<<<NPIX / 256, 1024, 0, stream>>>(sums, hist, proto, feat, logits, sumsq);
  k5_loss<<<64, 256, 0, stream>>>((const float4*)logits, (const uchar4*)lab, sumsq, lossacc,
                                  done, (float*)d_out);
}